// Round 8
// baseline (194.890 us; speedup 1.0000x reference)
//
#include <hip/hip_runtime.h>

typedef __attribute__((ext_vector_type(8))) short short8;
typedef __attribute__((ext_vector_type(4))) float float4v;
typedef __attribute__((ext_vector_type(4))) unsigned short us4;
typedef __attribute__((ext_vector_type(4))) unsigned int uint4v;

namespace {
constexpr int NG   = 16;
constexpr int LSEQ = 4096;
constexpr int CIN  = 1024;
constexpr int IPG  = 64;
constexpr int OPG  = 64;
constexpr int KT   = 5;
constexpr int KSTEPS = 10;                 // 320 K / 32
constexpr size_t WFRAG_SHORTS = (size_t)NG * 4 * KSTEPS * 512;  // 327,680
constexpr size_t WFRAG_BYTES  = WFRAG_SHORTS * 2;               // 655,360
constexpr size_t MASK_BYTES   = (size_t)4 * LSEQ;               // 16,384
}

__device__ __forceinline__ unsigned short f2bf(float f) {
  unsigned int u = __builtin_bit_cast(unsigned int, f);
  u += 0x7fffu + ((u >> 16) & 1u);   // RNE (inputs finite)
  return (unsigned short)(u >> 16);
}

// ---------------- fused prep: W-frag repack (blocks 0..159) + masks (160..223)
__global__ __launch_bounds__(256) void prep_fused(const float* __restrict__ gwt,
                                                  const int* __restrict__ gpos,
                                                  unsigned short* __restrict__ wfrag,
                                                  unsigned char* __restrict__ gmask) {
  if (blockIdx.x < 160) {
    const int u = blockIdx.x * 256 + threadIdx.x;           // 40960 threads
    const int E    = u * 8;
    const int tile = E >> 9;
    const int w9   = E & 511;
    const int n    = w9 >> 5;
    const int quad = (w9 & 31) >> 3;
    const int ks   = tile % KSTEPS;
    const int tt   = tile / KSTEPS;
    const int t    = tt & 3;
    const int g    = tt >> 2;
    const int tap  = ks >> 1;
    const int h    = ks & 1;
    const int o    = t * 16 + n;
    const float* src = gwt + (((size_t)(g * 64 + o) * 64) + h * 32 + quad * 8) * KT + tap;
    short8 v;
    #pragma unroll
    for (int j = 0; j < 8; ++j)
      v[j] = (short)f2bf(src[j * KT]);
    *(short8*)(wfrag + E) = v;
  } else {
    const int id = (blockIdx.x - 160) * 256 + threadIdx.x;  // 16384 threads
    const int b  = id >> 12;
    const int l  = id & (LSEQ - 1);
    const int base = b * LSEQ;
    const int pc = gpos[base + l];
    unsigned int mbits = 0;
    #pragma unroll
    for (int tap = 0; tap < KT; ++tap) {
      const int lsrc = l + tap - 2;
      int ok = 0;
      if (lsrc >= 0 && lsrc < LSEQ)
        ok = (gpos[base + lsrc] == pc + (tap - 2));
      mbits |= (unsigned int)ok << tap;
    }
    gmask[id] = (unsigned char)mbits;
  }
}

// ---------------- main v9: NO LDS — A-fragments direct from global -----------
// R0-R7 lesson: every LDS-staged structure (reg-staged, DMA'd, barriered or
// not, 2/4/8 blocks/CU) lands at 41-47 µs ≈ 2.3-2.7 TB/s, because each wave
// has an all-or-nothing vmcnt drain between staging and compute — read-pipe
// duty cycle ~50% no matter the arrangement. But the per-wave A-tile is only
// 9.2 KB unique with 5x tap-reuse, largely L1/L2/L3-resident (FETCH already
// shows ~50% cache hits). So: skip LDS entirely (Common-mistake #7). Each
// (ks,mt) step loads its A-fragment straight from gin — same 2x dwordx4 per
// lane as the old ds_read_b128 pair, coalesced within 128B lines — cvt_pk to
// bf16, mask, MFMA. No barrier, no DMA, no drain anywhere; short dependent
// chains + TLP hide cache latency (the fill kernel's mechanism). Low VGPR is
// now an asset (more waves), not a pipeline-killer: there is no staging batch
// for the RA to sink.
__global__ __launch_bounds__(256) void mconv_main9(
    const float* __restrict__ gin,            // (4,4096,1024) fp32
    const unsigned char* __restrict__ gmask,  // (4,4096) mask bytes
    const unsigned short* __restrict__ wfrag, // bf16 frag buffer
    float* __restrict__ gout) {               // (4,4096,16,64) fp32
  const int tid  = threadIdx.x;
  const int wv   = tid >> 6;
  const int lane = tid & 63;
  const int quad = lane >> 4;
  const int l16  = lane & 15;
  const int wm   = wv & 1;        // M half: rows [wm*32, wm*32+32)
  const int wn   = wv >> 1;       // N half: cols [wn*32, wn*32+32)

  const int g  = blockIdx.y;
  const int b  = blockIdx.z;
  const int l0 = blockIdx.x * 64;           // block: 64 rows x 64 cols
  const int bL = b * LSEQ;

  const float* ginb = gin + (size_t)bL * CIN + g * IPG + quad * 8;

  // ---- masks (L2-hot byte loads)
  int mb[2];
  #pragma unroll
  for (int mt = 0; mt < 2; ++mt)
    mb[mt] = gmask[bL + l0 + wm * 32 + mt * 16 + l16];

  // ---- B-frag stream bases (2 streams per wave), register prefetch depth 1
  const int laneoff = l16 * 32 + quad * 8;
  const unsigned short* wb0 = wfrag + (size_t)((g * 4 + wn * 2) * KSTEPS) * 512 + laneoff;
  const unsigned short* wb1 = wb0 + (size_t)KSTEPS * 512;

  const short8 zero8 = {0, 0, 0, 0, 0, 0, 0, 0};
  const float4v zf = {0.f, 0.f, 0.f, 0.f};
  float4v acc[2][2];
  #pragma unroll
  for (int mt = 0; mt < 2; ++mt) { acc[mt][0] = zf; acc[mt][1] = zf; }

  short8 bc0 = *(const short8*)(wb0);
  short8 bc1 = *(const short8*)(wb1);

  // per-mt clamped base rows (clamped rows are zeroed by mask bits)
  int lbase[2];
  #pragma unroll
  for (int mt = 0; mt < 2; ++mt)
    lbase[mt] = l0 + wm * 32 + mt * 16 + l16 - 2;    // + tap in [0,4]

  #pragma unroll
  for (int ks = 0; ks < KSTEPS; ++ks) {
    const int ksn = (ks + 1 < KSTEPS) ? ks + 1 : KSTEPS - 1;
    short8 bn0 = *(const short8*)(wb0 + ksn * 512);
    short8 bn1 = *(const short8*)(wb1 + ksn * 512);
    const int tap = ks >> 1;
    const int h   = ks & 1;
    #pragma unroll
    for (int mt = 0; mt < 2; ++mt) {
      int l = lbase[mt] + tap;
      l = l < 0 ? 0 : (l > LSEQ - 1 ? LSEQ - 1 : l);
      const float* p = ginb + (size_t)l * CIN + h * 32;
      float4v lo = *(const float4v*)(p);
      float4v hi = *(const float4v*)(p + 4);
      unsigned int d0, d1, d2, d3;
      asm("v_cvt_pk_bf16_f32 %0, %1, %2" : "=v"(d0) : "v"(lo[0]), "v"(lo[1]));
      asm("v_cvt_pk_bf16_f32 %0, %1, %2" : "=v"(d1) : "v"(lo[2]), "v"(lo[3]));
      asm("v_cvt_pk_bf16_f32 %0, %1, %2" : "=v"(d2) : "v"(hi[0]), "v"(hi[1]));
      asm("v_cvt_pk_bf16_f32 %0, %1, %2" : "=v"(d3) : "v"(hi[2]), "v"(hi[3]));
      uint4v dv = {d0, d1, d2, d3};
      short8 a = __builtin_bit_cast(short8, dv);
      if (!((mb[mt] >> tap) & 1)) a = zero8;
      acc[mt][0] = __builtin_amdgcn_mfma_f32_16x16x32_bf16(a, bc0, acc[mt][0], 0, 0, 0);
      acc[mt][1] = __builtin_amdgcn_mfma_f32_16x16x32_bf16(a, bc1, acc[mt][1], 0, 0, 0);
    }
    bc0 = bn0; bc1 = bn1;
  }

  // ---- epilogue: C/D layout col=l16, row=quad*4+reg
  #pragma unroll
  for (int mt = 0; mt < 2; ++mt) {
    const int lrow = l0 + wm * 32 + mt * 16 + quad * 4;
    #pragma unroll
    for (int reg = 0; reg < 4; ++reg) {
      float* orow = gout + (size_t)(bL + lrow + reg) * CIN + g * OPG + wn * 32;
      orow[l16]      = acc[mt][0][reg];
      orow[16 + l16] = acc[mt][1][reg];
    }
  }
}

// ---------------- fallback (known-good R3 kernel, used if ws too small) -----
namespace fb {
constexpr int ROWS_PER_CHUNK = 128;
constexpr int CHUNKS = 4;
constexpr int ROWS_PER_BLOCK = 512;
constexpr int SW_STRIDE  = 328;
constexpr int FSIN_STRIDE = 72;
constexpr int FSIN_ROWS   = 132;
}

__global__ __launch_bounds__(256, 2) void mconv_f32_mfma(
    const float* __restrict__ gin, const int* __restrict__ gpos,
    const float* __restrict__ gwt, float* __restrict__ gout) {
  using namespace fb;
  __shared__ __align__(16) unsigned short sW[OPG * SW_STRIDE];
  __shared__ __align__(16) unsigned short sIn[FSIN_ROWS * FSIN_STRIDE];
  __shared__ unsigned char sMask[ROWS_PER_CHUNK * KT];

  const int tid  = threadIdx.x;
  const int wave = tid >> 6;
  const int lane = tid & 63;
  const int quad = lane >> 4;
  const int l16  = lane & 15;
  const int g  = blockIdx.y;
  const int b  = blockIdx.z;
  const int tile0 = blockIdx.x * ROWS_PER_BLOCK;
  const int bL = b * LSEQ;

  {
    const float* wg = gwt + (size_t)g * (OPG * IPG * KT);
    for (int u = tid; u < (OPG * IPG * KT) / 4; u += 256) {
      const int base = u * 4;
      float4v v = *(const float4v*)(wg + base);
      int o = base / (IPG * KT);
      int r = base - o * (IPG * KT);
      int i = r / KT;
      int k = r - i * KT;
      int addr = o * SW_STRIDE + k * IPG + i;
      #pragma unroll
      for (int t = 0; t < 4; ++t) {
        sW[addr] = f2bf(v[t]);
        ++k; addr += IPG;
        if (k == KT) { k = 0; ++i; addr -= KT * IPG - 1; }
      }
    }
  }
  const short8 zero8 = {0,0,0,0,0,0,0,0};
  const float4v zf = {0.f,0.f,0.f,0.f};
  for (int ch = 0; ch < CHUNKS; ++ch) {
    const int l0 = tile0 + ch * ROWS_PER_CHUNK;
    __syncthreads();
    for (int t = tid; t < ROWS_PER_CHUNK * KT; t += 256) {
      const int lr = t / KT, tap = t - lr * KT, l = l0 + lr, lsrc = l + tap - 2;
      int ok = 0;
      if (lsrc >= 0 && lsrc < LSEQ) ok = (gpos[bL + lsrc] == gpos[bL + l] + (tap - 2));
      sMask[t] = (unsigned char)ok;
    }
    for (int u = tid; u < FSIN_ROWS * 16; u += 256) {
      const int r = u >> 4, c4 = u & 15, l = l0 - 2 + r;
      us4 w = {0,0,0,0};
      if (l >= 0 && l < LSEQ) {
        float4v v = *(const float4v*)(gin + (size_t)(bL + l) * CIN + g * IPG + c4 * 4);
        w[0]=f2bf(v[0]); w[1]=f2bf(v[1]); w[2]=f2bf(v[2]); w[3]=f2bf(v[3]);
      }
      *(us4*)(&sIn[r * FSIN_STRIDE + c4 * 4]) = w;
    }
    __syncthreads();
    float4v acc[2][4];
    #pragma unroll
    for (int mm = 0; mm < 2; ++mm)
      #pragma unroll
      for (int nt = 0; nt < 4; ++nt) acc[mm][nt] = zf;
    const int m0 = wave * 32 + l16, m1 = m0 + 16;
    #pragma unroll
    for (int tap = 0; tap < KT; ++tap) {
      const bool msk0 = sMask[m0 * KT + tap] != 0;
      const bool msk1 = sMask[m1 * KT + tap] != 0;
      #pragma unroll
      for (int h = 0; h < 2; ++h) {
        const int kk = tap * IPG + h * 32 + quad * 8;
        const short8 b0 = *(const short8*)(&sW[(0*16 + l16) * SW_STRIDE + kk]);
        const short8 b1 = *(const short8*)(&sW[(1*16 + l16) * SW_STRIDE + kk]);
        const short8 b2 = *(const short8*)(&sW[(2*16 + l16) * SW_STRIDE + kk]);
        const short8 b3 = *(const short8*)(&sW[(3*16 + l16) * SW_STRIDE + kk]);
        const int ci = h * 32 + quad * 8;
        short8 a0 = *(const short8*)(&sIn[(m0 + tap) * FSIN_STRIDE + ci]);
        short8 a1 = *(const short8*)(&sIn[(m1 + tap) * FSIN_STRIDE + ci]);
        if (!msk0) a0 = zero8;
        if (!msk1) a1 = zero8;
        acc[0][0] = __builtin_amdgcn_mfma_f32_16x16x32_bf16(a0,b0,acc[0][0],0,0,0);
        acc[0][1] = __builtin_amdgcn_mfma_f32_16x16x32_bf16(a0,b1,acc[0][1],0,0,0);
        acc[0][2] = __builtin_amdgcn_mfma_f32_16x16x32_bf16(a0,b2,acc[0][2],0,0,0);
        acc[0][3] = __builtin_amdgcn_mfma_f32_16x16x32_bf16(a0,b3,acc[0][3],0,0,0);
        acc[1][0] = __builtin_amdgcn_mfma_f32_16x16x32_bf16(a1,b0,acc[1][0],0,0,0);
        acc[1][1] = __builtin_amdgcn_mfma_f32_16x16x32_bf16(a1,b1,acc[1][1],0,0,0);
        acc[1][2] = __builtin_amdgcn_mfma_f32_16x16x32_bf16(a1,b2,acc[1][2],0,0,0);
        acc[1][3] = __builtin_amdgcn_mfma_f32_16x16x32_bf16(a1,b3,acc[1][3],0,0,0);
      }
    }
    #pragma unroll
    for (int mm = 0; mm < 2; ++mm) {
      const int lrow = l0 + wave * 32 + mm * 16 + quad * 4;
      #pragma unroll
      for (int reg = 0; reg < 4; ++reg) {
        float* orow = gout + ((size_t)(bL + lrow + reg) * NG + g) * OPG;
        #pragma unroll
        for (int nt = 0; nt < 4; ++nt)
          orow[nt * 16 + l16] = acc[mm][nt][reg];
      }
    }
  }
}

extern "C" void kernel_launch(void* const* d_in, const int* in_sizes, int n_in,
                              void* d_out, int out_size, void* d_ws, size_t ws_size,
                              hipStream_t stream) {
  (void)in_sizes; (void)n_in; (void)out_size;
  const float* gin  = (const float*)d_in[0];
  const int*   gpos = (const int*)d_in[1];
  const float* gwt  = (const float*)d_in[2];
  float*       gout = (float*)d_out;

  if (ws_size >= WFRAG_BYTES + MASK_BYTES) {
    unsigned short* wfrag = (unsigned short*)d_ws;
    unsigned char*  gmask = (unsigned char*)d_ws + WFRAG_BYTES;
    hipLaunchKernelGGL(prep_fused, dim3(224), dim3(256), 0, stream,
                       gwt, gpos, wfrag, gmask);
    dim3 grid(LSEQ / 64, NG, 4);   // 64 x 16 x 4 = 4096 blocks
    hipLaunchKernelGGL(mconv_main9, grid, dim3(256), 0, stream,
                       gin, gmask, wfrag, gout);
  } else {
    dim3 grid(LSEQ / fb::ROWS_PER_BLOCK, NG, 4);
    hipLaunchKernelGGL(mconv_f32_mfma, grid, dim3(256), 0, stream,
                       gin, gpos, gwt, gout);
  }
}

// Round 9
// 135.579 us; speedup vs baseline: 1.4375x; 1.4375x over previous
//
#include <hip/hip_runtime.h>

typedef __attribute__((ext_vector_type(8))) short short8;
typedef __attribute__((ext_vector_type(4))) float float4v;
typedef __attribute__((ext_vector_type(4))) unsigned short us4;
typedef __attribute__((ext_vector_type(4))) unsigned int uint4v;

namespace {
constexpr int NG   = 16;
constexpr int LSEQ = 4096;
constexpr int CIN  = 1024;
constexpr int IPG  = 64;
constexpr int OPG  = 64;
constexpr int KT   = 5;
constexpr int WROWS = 32;                  // output rows per wave-tile
constexpr int SROWS = WROWS + KT - 1;      // 36 staged rows
constexpr int WSLOTS = SROWS * 16;         // 576 16B slots (9,216 B) per buffer
constexpr int TILES = 4;                   // tiles per wave (persistent)
constexpr int KSTEPS = 10;                 // 320 K / 32
constexpr size_t WFRAG_SHORTS = (size_t)NG * 4 * KSTEPS * 512;  // 327,680
constexpr size_t WFRAG_BYTES  = WFRAG_SHORTS * 2;               // 655,360
constexpr size_t MASK_BYTES   = (size_t)4 * LSEQ;               // 16,384
}

__device__ __forceinline__ unsigned short f2bf(float f) {
  unsigned int u = __builtin_bit_cast(unsigned int, f);
  u += 0x7fffu + ((u >> 16) & 1u);   // RNE (inputs finite)
  return (unsigned short)(u >> 16);
}

// ---------------- fused prep: W-frag repack (blocks 0..159) + masks (160..223)
__global__ __launch_bounds__(256) void prep_fused(const float* __restrict__ gwt,
                                                  const int* __restrict__ gpos,
                                                  unsigned short* __restrict__ wfrag,
                                                  unsigned char* __restrict__ gmask) {
  if (blockIdx.x < 160) {
    const int u = blockIdx.x * 256 + threadIdx.x;           // 40960 threads
    const int E    = u * 8;
    const int tile = E >> 9;
    const int w9   = E & 511;
    const int n    = w9 >> 5;
    const int quad = (w9 & 31) >> 3;
    const int ks   = tile % KSTEPS;
    const int tt   = tile / KSTEPS;
    const int t    = tt & 3;
    const int g    = tt >> 2;
    const int tap  = ks >> 1;
    const int h    = ks & 1;
    const int o    = t * 16 + n;
    const float* src = gwt + (((size_t)(g * 64 + o) * 64) + h * 32 + quad * 8) * KT + tap;
    short8 v;
    #pragma unroll
    for (int j = 0; j < 8; ++j)
      v[j] = (short)f2bf(src[j * KT]);
    *(short8*)(wfrag + E) = v;
  } else {
    const int id = (blockIdx.x - 160) * 256 + threadIdx.x;  // 16384 threads
    const int b  = id >> 12;
    const int l  = id & (LSEQ - 1);
    const int base = b * LSEQ;
    const int pc = gpos[base + l];
    unsigned int mbits = 0;
    #pragma unroll
    for (int tap = 0; tap < KT; ++tap) {
      const int lsrc = l + tap - 2;
      int ok = 0;
      if (lsrc >= 0 && lsrc < LSEQ)
        ok = (gpos[base + lsrc] == pc + (tap - 2));
      mbits |= (unsigned int)ok << tap;
    }
    gmask[id] = (unsigned char)mbits;
  }
}

// ---------------- main v10: per-wave pipelined DMA double-buffer -------------
// R8 proved A-fragments MUST come from LDS (row-scattered global reads are
// request-rate bound: 107 µs). R0-R7 proved the all-or-nothing drain between a
// wave's only load burst and its only compute phase caps LDS-staged variants
// at 41-47 µs. Fix uses only SAFE primitives: vmcnt is PER-WAVE, and each wave
// owns a PRIVATE double-buffered LDS region (R7 structure), so
//   issue DMA(t+1 -> other buf) ; compute(t) ; s_waitcnt vmcnt(0)
// is race-free BY PROGRAM ORDER: the full drain is exact (no counting — R4's
// failure mode impossible) and cheap (DMAs had the whole compute phase to
// land). No barrier in the kernel. Worst case (compiler sinks the issue) is
// R7's 46 µs, never incorrect. Persistent waves: 4 tiles each, grid 512 =
// exactly 2 blocks/CU resident, no tail.
__global__ __launch_bounds__(256) void mconv_main10(
    const float* __restrict__ gin,            // (4,4096,1024) fp32
    const unsigned char* __restrict__ gmask,  // (4,4096) mask bytes
    const unsigned short* __restrict__ wfrag, // bf16 frag buffer
    float* __restrict__ gout) {               // (4,4096,16,64) fp32
  __shared__ __align__(16) float sIn[4][2][WSLOTS * 4];   // 73,728 B, wave-private

  const int tid  = threadIdx.x;
  const int wv   = tid >> 6;
  const int lane = tid & 63;
  const int quad = lane >> 4;
  const int l16  = lane & 15;

  const int g  = blockIdx.y;
  const int b  = blockIdx.z;
  const int bL = b * LSEQ;
  const int lblk = blockIdx.x * (WROWS * 4 * TILES);   // 512 rows per block

  const float* ginb = gin + (size_t)bL * CIN + g * IPG;

  // tile t row base for this wave
  auto tbase = [&](int t) { return lblk + t * (WROWS * 4) + wv * WROWS; };

  // ---- 9 DMAs per lane into private buffer: slot u -> (row r, phys slot ps),
  //      logical col c4 = ps ^ (r&15) (swizzle on GLOBAL SOURCE; linear dest).
  auto issue = [&](int buf, int l0w) {
    #pragma unroll
    for (int k = 0; k < 9; ++k) {
      const int u  = lane + k * 64;                  // 576 slots exactly
      const int r  = u >> 4;
      const int ps = u & 15;
      const int c4 = ps ^ (r & 15);
      int l = l0w - 2 + r;
      l = l < 0 ? 0 : (l > LSEQ - 1 ? LSEQ - 1 : l); // clamped rows masked at use
      const float* src = ginb + (size_t)l * CIN + c4 * 4;
      __builtin_amdgcn_global_load_lds(
          (const __attribute__((address_space(1))) void*)(const void*)src,
          (__attribute__((address_space(3))) void*)(void*)&sIn[wv][buf][u * 4],
          16, 0, 0);
    }
  };

  // ---- B-frag stream bases (tile-invariant: same g for all tiles)
  const int laneoff = l16 * 32 + quad * 8;
  const unsigned short* wb[4];
  #pragma unroll
  for (int nt = 0; nt < 4; ++nt)
    wb[nt] = wfrag + (size_t)((g * 4 + nt) * KSTEPS) * 512 + laneoff;

  const short8 zero8 = {0, 0, 0, 0, 0, 0, 0, 0};
  const float4v zf = {0.f, 0.f, 0.f, 0.f};

  auto compute_store = [&](int buf, int l0w, int m0, int m1) {
    float4v acc[2][4];
    #pragma unroll
    for (int mt = 0; mt < 2; ++mt)
      #pragma unroll
      for (int nt = 0; nt < 4; ++nt) acc[mt][nt] = zf;
    short8 bc[4], bn[4];
    #pragma unroll
    for (int nt = 0; nt < 4; ++nt) bc[nt] = *(const short8*)(wb[nt]);
    const int mb[2] = {m0, m1};
    #pragma unroll 2
    for (int ks = 0; ks < KSTEPS; ++ks) {
      const int ksn = (ks + 1 < KSTEPS) ? ks + 1 : KSTEPS - 1;
      #pragma unroll
      for (int nt = 0; nt < 4; ++nt)
        bn[nt] = *(const short8*)(wb[nt] + ksn * 512);
      const int tap = ks >> 1;
      const int h   = ks & 1;
      const int ls  = h * 8 + quad * 2;               // even logical 16B slot
      #pragma unroll
      for (int mt = 0; mt < 2; ++mt) {
        const int lr  = mt * 16 + l16 + tap;          // local row 0..35
        const int swz = lr & 15;
        const float* rowp = &sIn[wv][buf][lr * 64];
        float4v lo = *(const float4v*)(rowp + ((ls ^ swz) << 2));
        float4v hi = *(const float4v*)(rowp + (((ls + 1) ^ swz) << 2));
        unsigned int d0, d1, d2, d3;
        asm("v_cvt_pk_bf16_f32 %0, %1, %2" : "=v"(d0) : "v"(lo[0]), "v"(lo[1]));
        asm("v_cvt_pk_bf16_f32 %0, %1, %2" : "=v"(d1) : "v"(lo[2]), "v"(lo[3]));
        asm("v_cvt_pk_bf16_f32 %0, %1, %2" : "=v"(d2) : "v"(hi[0]), "v"(hi[1]));
        asm("v_cvt_pk_bf16_f32 %0, %1, %2" : "=v"(d3) : "v"(hi[2]), "v"(hi[3]));
        uint4v dv = {d0, d1, d2, d3};
        short8 a = __builtin_bit_cast(short8, dv);
        if (!((mb[mt] >> tap) & 1)) a = zero8;
        acc[mt][0] = __builtin_amdgcn_mfma_f32_16x16x32_bf16(a, bc[0], acc[mt][0], 0, 0, 0);
        acc[mt][1] = __builtin_amdgcn_mfma_f32_16x16x32_bf16(a, bc[1], acc[mt][1], 0, 0, 0);
        acc[mt][2] = __builtin_amdgcn_mfma_f32_16x16x32_bf16(a, bc[2], acc[mt][2], 0, 0, 0);
        acc[mt][3] = __builtin_amdgcn_mfma_f32_16x16x32_bf16(a, bc[3], acc[mt][3], 0, 0, 0);
      }
      #pragma unroll
      for (int nt = 0; nt < 4; ++nt) bc[nt] = bn[nt];
    }
    // epilogue: C/D layout col=l16, row=quad*4+reg
    #pragma unroll
    for (int mt = 0; mt < 2; ++mt) {
      const int lrow = l0w + mt * 16 + quad * 4;
      #pragma unroll
      for (int reg = 0; reg < 4; ++reg) {
        float* orow = gout + (size_t)(bL + lrow + reg) * CIN + g * OPG;
        #pragma unroll
        for (int nt = 0; nt < 4; ++nt)
          orow[nt * 16 + l16] = acc[mt][nt][reg];
      }
    }
  };

  // ---- prologue: stage tile 0, load its masks, exact per-wave drain
  issue(0, tbase(0));
  int m0 = gmask[bL + tbase(0) + l16];
  int m1 = gmask[bL + tbase(0) + 16 + l16];
  asm volatile("s_waitcnt vmcnt(0)" ::: "memory");

  // ---- pipelined persistent loop over 4 tiles
  #pragma unroll
  for (int t = 0; t < TILES; ++t) {
    const int cur = t & 1;
    int nm0 = 0, nm1 = 0;
    if (t + 1 < TILES) {
      issue(cur ^ 1, tbase(t + 1));               // next-tile DMA in flight
      nm0 = gmask[bL + tbase(t + 1) + l16];
      nm1 = gmask[bL + tbase(t + 1) + 16 + l16];
      __builtin_amdgcn_sched_barrier(0);          // pin issue above compute
    }
    compute_store(cur, tbase(t), m0, m1);
    asm volatile("s_waitcnt vmcnt(0)" ::: "memory");  // exact drain: DMAs landed
    m0 = nm0; m1 = nm1;
  }
}

// ---------------- fallback (known-good R3 kernel, used if ws too small) -----
namespace fb {
constexpr int ROWS_PER_CHUNK = 128;
constexpr int CHUNKS = 4;
constexpr int ROWS_PER_BLOCK = 512;
constexpr int SW_STRIDE  = 328;
constexpr int FSIN_STRIDE = 72;
constexpr int FSIN_ROWS   = 132;
}

__global__ __launch_bounds__(256, 2) void mconv_f32_mfma(
    const float* __restrict__ gin, const int* __restrict__ gpos,
    const float* __restrict__ gwt, float* __restrict__ gout) {
  using namespace fb;
  __shared__ __align__(16) unsigned short sW[OPG * SW_STRIDE];
  __shared__ __align__(16) unsigned short sIn[FSIN_ROWS * FSIN_STRIDE];
  __shared__ unsigned char sMask[ROWS_PER_CHUNK * KT];

  const int tid  = threadIdx.x;
  const int wave = tid >> 6;
  const int lane = tid & 63;
  const int quad = lane >> 4;
  const int l16  = lane & 15;
  const int g  = blockIdx.y;
  const int b  = blockIdx.z;
  const int tile0 = blockIdx.x * ROWS_PER_BLOCK;
  const int bL = b * LSEQ;

  {
    const float* wg = gwt + (size_t)g * (OPG * IPG * KT);
    for (int u = tid; u < (OPG * IPG * KT) / 4; u += 256) {
      const int base = u * 4;
      float4v v = *(const float4v*)(wg + base);
      int o = base / (IPG * KT);
      int r = base - o * (IPG * KT);
      int i = r / KT;
      int k = r - i * KT;
      int addr = o * SW_STRIDE + k * IPG + i;
      #pragma unroll
      for (int t = 0; t < 4; ++t) {
        sW[addr] = f2bf(v[t]);
        ++k; addr += IPG;
        if (k == KT) { k = 0; ++i; addr -= KT * IPG - 1; }
      }
    }
  }
  const short8 zero8 = {0,0,0,0,0,0,0,0};
  const float4v zf = {0.f,0.f,0.f,0.f};
  for (int ch = 0; ch < CHUNKS; ++ch) {
    const int l0 = tile0 + ch * ROWS_PER_CHUNK;
    __syncthreads();
    for (int t = tid; t < ROWS_PER_CHUNK * KT; t += 256) {
      const int lr = t / KT, tap = t - lr * KT, l = l0 + lr, lsrc = l + tap - 2;
      int ok = 0;
      if (lsrc >= 0 && lsrc < LSEQ) ok = (gpos[bL + lsrc] == gpos[bL + l] + (tap - 2));
      sMask[t] = (unsigned char)ok;
    }
    for (int u = tid; u < FSIN_ROWS * 16; u += 256) {
      const int r = u >> 4, c4 = u & 15, l = l0 - 2 + r;
      us4 w = {0,0,0,0};
      if (l >= 0 && l < LSEQ) {
        float4v v = *(const float4v*)(gin + (size_t)(bL + l) * CIN + g * IPG + c4 * 4);
        w[0]=f2bf(v[0]); w[1]=f2bf(v[1]); w[2]=f2bf(v[2]); w[3]=f2bf(v[3]);
      }
      *(us4*)(&sIn[r * FSIN_STRIDE + c4 * 4]) = w;
    }
    __syncthreads();
    float4v acc[2][4];
    #pragma unroll
    for (int mm = 0; mm < 2; ++mm)
      #pragma unroll
      for (int nt = 0; nt < 4; ++nt) acc[mm][nt] = zf;
    const int m0 = wave * 32 + l16, m1 = m0 + 16;
    #pragma unroll
    for (int tap = 0; tap < KT; ++tap) {
      const bool msk0 = sMask[m0 * KT + tap] != 0;
      const bool msk1 = sMask[m1 * KT + tap] != 0;
      #pragma unroll
      for (int h = 0; h < 2; ++h) {
        const int kk = tap * IPG + h * 32 + quad * 8;
        const short8 b0 = *(const short8*)(&sW[(0*16 + l16) * SW_STRIDE + kk]);
        const short8 b1 = *(const short8*)(&sW[(1*16 + l16) * SW_STRIDE + kk]);
        const short8 b2 = *(const short8*)(&sW[(2*16 + l16) * SW_STRIDE + kk]);
        const short8 b3 = *(const short8*)(&sW[(3*16 + l16) * SW_STRIDE + kk]);
        const int ci = h * 32 + quad * 8;
        short8 a0 = *(const short8*)(&sIn[(m0 + tap) * FSIN_STRIDE + ci]);
        short8 a1 = *(const short8*)(&sIn[(m1 + tap) * FSIN_STRIDE + ci]);
        if (!msk0) a0 = zero8;
        if (!msk1) a1 = zero8;
        acc[0][0] = __builtin_amdgcn_mfma_f32_16x16x32_bf16(a0,b0,acc[0][0],0,0,0);
        acc[0][1] = __builtin_amdgcn_mfma_f32_16x16x32_bf16(a0,b1,acc[0][1],0,0,0);
        acc[0][2] = __builtin_amdgcn_mfma_f32_16x16x32_bf16(a0,b2,acc[0][2],0,0,0);
        acc[0][3] = __builtin_amdgcn_mfma_f32_16x16x32_bf16(a0,b3,acc[0][3],0,0,0);
        acc[1][0] = __builtin_amdgcn_mfma_f32_16x16x32_bf16(a1,b0,acc[1][0],0,0,0);
        acc[1][1] = __builtin_amdgcn_mfma_f32_16x16x32_bf16(a1,b1,acc[1][1],0,0,0);
        acc[1][2] = __builtin_amdgcn_mfma_f32_16x16x32_bf16(a1,b2,acc[1][2],0,0,0);
        acc[1][3] = __builtin_amdgcn_mfma_f32_16x16x32_bf16(a1,b3,acc[1][3],0,0,0);
      }
    }
    #pragma unroll
    for (int mm = 0; mm < 2; ++mm) {
      const int lrow = l0 + wave * 32 + mm * 16 + quad * 4;
      #pragma unroll
      for (int reg = 0; reg < 4; ++reg) {
        float* orow = gout + ((size_t)(bL + lrow + reg) * NG + g) * OPG;
        #pragma unroll
        for (int nt = 0; nt < 4; ++nt)
          orow[nt * 16 + l16] = acc[mm][nt][reg];
      }
    }
  }
}

extern "C" void kernel_launch(void* const* d_in, const int* in_sizes, int n_in,
                              void* d_out, int out_size, void* d_ws, size_t ws_size,
                              hipStream_t stream) {
  (void)in_sizes; (void)n_in; (void)out_size;
  const float* gin  = (const float*)d_in[0];
  const int*   gpos = (const int*)d_in[1];
  const float* gwt  = (const float*)d_in[2];
  float*       gout = (float*)d_out;

  if (ws_size >= WFRAG_BYTES + MASK_BYTES) {
    unsigned short* wfrag = (unsigned short*)d_ws;
    unsigned char*  gmask = (unsigned char*)d_ws + WFRAG_BYTES;
    hipLaunchKernelGGL(prep_fused, dim3(224), dim3(256), 0, stream,
                       gwt, gpos, wfrag, gmask);
    dim3 grid(LSEQ / (WROWS * 4 * TILES), NG, 4);   // 8 x 16 x 4 = 512 blocks
    hipLaunchKernelGGL(mconv_main10, grid, dim3(256), 0, stream,
                       gin, gmask, wfrag, gout);
  } else {
    dim3 grid(LSEQ / fb::ROWS_PER_BLOCK, NG, 4);
    hipLaunchKernelGGL(mconv_f32_mfma, grid, dim3(256), 0, stream,
                       gin, gpos, gwt, gout);
  }
}